// Round 4
// baseline (1181.164 us; speedup 1.0000x reference)
//
#include <hip/hip_runtime.h>
#include <math.h>

#define PIX 4096      // 64*64
#define NPIX 65536    // B*H*W
#define EPS 1e-5f
#define NBLK 256u

typedef _Float16 half8 __attribute__((ext_vector_type(8)));
typedef float floatx16 __attribute__((ext_vector_type(16)));

__device__ __forceinline__ float gelu_f(float x) {
    return 0.5f * x * (1.0f + erff(x * 0.70710678118654752f));
}

// one-shot grid barrier: each slot used exactly once per launch, pre-zeroed by memsetAsync.
__device__ __forceinline__ void gbar(unsigned* cnt) {
    __threadfence();          // release: publish this block's global writes (device scope)
    __syncthreads();
    if (threadIdx.x == 0) {
        __hip_atomic_fetch_add(cnt, 1u, __ATOMIC_ACQ_REL, __HIP_MEMORY_SCOPE_AGENT);
        while (__hip_atomic_load(cnt, __ATOMIC_ACQUIRE, __HIP_MEMORY_SCOPE_AGENT) < NBLK) {
            __builtin_amdgcn_s_sleep(1);
        }
    }
    __syncthreads();
    __threadfence();          // acquire: invalidate so subsequent loads see remote writes
}

struct FusedArgs {
    const float *x, *cond;
    const float *bn2_g, *bn2_b, *bn1_g, *bn1_b;
    const float *b_w1, *b_b1, *b_w2, *b_b2, *b_w3, *b_b3;
    const float *l1w, *l1b, *l2w, *l2b;
    const float *sw1r, *sw1i, *sw2r, *sw2i, *skw, *skb;
    const float *p2w;
    unsigned *bar;
    float *brn, *t0, *t1;
    float2 *A, *O;
    float *spec;
    _Float16 *wt;
};

// DFT along w (64 -> 16 modes) from an LDS tile (64x65 padded)
__device__ __forceinline__ void fwd_w_tile(const float* s_tl, const float* ct, const float* st,
                                           int bc, float2* A, int tid) {
    for (int o = tid; o < 1024; o += 256) {
        int kw = o >> 6, h = o & 63;
        float xr = 0.f, xi = 0.f;
        for (int w = 0; w < 64; w++) {
            int j = (kw * w) & 63;
            float v = s_tl[h * 65 + w];
            xr += v * ct[j];
            xi -= v * st[j];
        }
        A[(bc * 16 + kw) * 64 + h] = make_float2(xr, xi);
    }
}

__global__ __launch_bounds__(256) void k_fused(FusedArgs a) {
    __shared__ float s_tl[64 * 65];    // 16640 B
    __shared__ float s_aux[3200];      // 12800 B (Al+Xl / Ol+Yl)
    __shared__ float ct[64], st[64];
    __shared__ float s_red[512];
    __shared__ float cms[4];
    int blk = blockIdx.x, tid = threadIdx.x;
    int bi = 0;

    if (tid < 64) { float s, c; sincospif(tid * (1.0f / 32.0f), &s, &c); ct[tid] = c; st[tid] = s; }

    // ---- P0a: BN2d stats (redundant per block; x is 256 KB, L2-resident) ----
    float bn_m, bn_istd;
    {
        float aa = 0.f, bb = 0.f;
        for (int i = tid; i < NPIX; i += 256) { float v = a.x[i]; aa += v; bb += v * v; }
        s_red[tid] = aa; s_red[256 + tid] = bb;
        __syncthreads();
        for (int off = 128; off > 0; off >>= 1) {
            if (tid < off) { s_red[tid] += s_red[tid + off]; s_red[256 + tid] += s_red[256 + tid + off]; }
            __syncthreads();
        }
        bn_m = s_red[0] * (1.0f / NPIX);
        float var = s_red[256] * (1.0f / NPIX) - bn_m * bn_m;
        bn_istd = rsqrtf(var + EPS);
    }

    // ---- P0b: p2w -> fp16 fragment layout (blocks 0..19) ----
    if (blk < 20) {
        int eg = blk;
        for (int idx = tid; idx < 1024; idx += 256) {
            int m = idx & 31, kh = (idx >> 5) & 1, ks = idx >> 6;
            half8 v;
#pragma unroll
            for (int j = 0; j < 8; j++)
                v[j] = (_Float16)a.p2w[(ks * 16 + kh * 8 + j) * 640 + eg * 32 + m];
            *(half8*)&a.wt[eg * 8192 + ks * 512 + kh * 256 + m * 8] = v;
        }
    }

    // ---- P0c: condition BN + branch MLP (block 255) ----
    if (blk == 255) {
        if (tid < 2) {
            float s = 0.f;
            for (int i = 0; i < 16; i++) s += a.cond[i * 2 + tid];
            float m = s / 16.f, v = 0.f;
            for (int i = 0; i < 16; i++) { float d = a.cond[i * 2 + tid] - m; v += d * d; }
            cms[tid] = m; cms[2 + tid] = rsqrtf(v / 16.f + EPS);
        }
        __syncthreads();
        if (tid < 16) {
            float c0 = (a.cond[tid * 2 + 0] - cms[0]) * cms[2] * a.bn1_g[0] + a.bn1_b[0];
            float c1 = (a.cond[tid * 2 + 1] - cms[1]) * cms[3] * a.bn1_g[1] + a.bn1_b[1];
            float h1[50], h2[50];
            for (int j = 0; j < 50; j++) h1[j] = tanhf(a.b_b1[j] + c0 * a.b_w1[j] + c1 * a.b_w1[50 + j]);
            for (int j = 0; j < 50; j++) {
                float acc = a.b_b2[j];
                for (int k = 0; k < 50; k++) acc += h1[k] * a.b_w2[k * 50 + j];
                h2[j] = tanhf(acc);
            }
            float acc = a.b_b3[0];
            for (int k = 0; k < 50; k++) acc += h2[k] * a.b_w3[k];
            a.brn[tid] = tanhf(acc);
        }
    }

    // ---- P0d: lifting (px-partitioned, 1 px/thread) ----
    {
        int p = blk * 256 + tid;
        float xn = (a.x[p] - bn_m) * bn_istd * a.bn2_g[0] + a.bn2_b[0];
        float acc[12];
#pragma unroll
        for (int e = 0; e < 12; e++) acc[e] = a.l2b[e];
        for (int d = 0; d < 256; d++) {
            float g = gelu_f(xn * a.l1w[d] + a.l1b[d]);
#pragma unroll
            for (int e = 0; e < 12; e++) acc[e] += g * a.l2w[d * 12 + e];
        }
        int b = p >> 12, px = p & 4095;
#pragma unroll
        for (int e = 0; e < 12; e++) a.t0[(b * 12 + e) * PIX + px] = acc[e];
    }
    gbar(&a.bar[bi++]);   // S1

    const float* tin = a.t0;
    float* tout = a.t1;

    // ---- P1: layer-0 fwd_w (units (b,c) = 192) ----
    if (blk < 192) {
        for (int i = tid; i < PIX; i += 256) s_tl[(i >> 6) * 65 + (i & 63)] = tin[blk * PIX + i];
        __syncthreads();
        fwd_w_tile(s_tl, ct, st, blk, a.A, tid);
    }
    gbar(&a.bar[bi++]);   // S2

    for (int l = 0; l < 4; l++) {
        const float* w1r = a.sw1r + l * 36864; const float* w1i = a.sw1i + l * 36864;
        const float* w2r = a.sw2r + l * 36864; const float* w2i = a.sw2i + l * 36864;

        // ---- P2: fwd DFT along h + spectral multiply (units (b,kw) = 256) ----
        {
            int b = blk >> 4, kw = blk & 15;
            float2* Al = (float2*)s_aux;            // 768 float2
            float2* Xl = (float2*)(s_aux + 1536);   // 384 float2
            for (int i = tid; i < 768; i += 256) {
                int c = i >> 6, h = i & 63;
                Al[i] = a.A[((b * 12 + c) * 16 + kw) * 64 + h];
            }
            __syncthreads();
            for (int o = tid; o < 384; o += 256) {
                int c = o >> 5, kh = o & 31;
                int f = (kh < 16) ? kh : kh + 32;
                float xr = 0.f, xi = 0.f;
                for (int h = 0; h < 64; h++) {
                    int j = (f * h) & 63;
                    float2 av = Al[c * 64 + h];
                    float cc = ct[j], ss = st[j];
                    xr += av.x * cc + av.y * ss;
                    xi += av.y * cc - av.x * ss;
                }
                Xl[c * 32 + kh] = make_float2(xr, xi);
            }
            __syncthreads();
            for (int o2 = tid; o2 < 384; o2 += 256) {
                int o = o2 >> 5, kh = o2 & 31;
                int khr = kh & 15;
                const float* wr = (kh < 16) ? w1r : w2r;
                const float* wi = (kh < 16) ? w1i : w2i;
                float orr = 0.f, oii = 0.f;
                for (int c = 0; c < 12; c++) {
                    float2 xv = Xl[c * 32 + kh];
                    int wIdx = ((c * 12 + o) * 16 + khr) * 16 + kw;
                    float wrv = wr[wIdx], wiv = wi[wIdx];
                    orr += xv.x * wrv - xv.y * wiv;
                    oii += xv.x * wiv + xv.y * wrv;
                }
                a.O[((b * 12 + o) * 32 + kh) * 16 + kw] = make_float2(orr, oii);
            }
        }
        gbar(&a.bar[bi++]);

        // ---- P3P4: inverse DFTs + skip (+gelu + next-layer fwd_w)  (units (b,o) = 192) ----
        if (blk < 192) {
            int b = blk / 12, oc = blk % 12;
            float2* Ol = (float2*)s_aux;            // 512 float2
            float2* Yl = (float2*)(s_aux + 1024);   // 1088 float2
            for (int i = tid; i < 512; i += 256) Ol[i] = a.O[blk * 512 + i];
            __syncthreads();
            for (int oidx = tid; oidx < 1024; oidx += 256) {
                int kw = oidx >> 6, h = oidx & 63;
                float yr = 0.f, yi = 0.f;
                for (int kh = 0; kh < 32; kh++) {
                    int f = (kh < 16) ? kh : kh + 32;
                    int j = (f * h) & 63;
                    float2 ov = Ol[kh * 16 + kw];
                    float cc = ct[j], ss = st[j];
                    yr += ov.x * cc - ov.y * ss;
                    yi += ov.x * ss + ov.y * cc;
                }
                Yl[h * 17 + kw] = make_float2(yr * (1.0f / 4096.0f), yi * (1.0f / 4096.0f));
            }
            __syncthreads();
            for (int i = tid; i < PIX; i += 256) {
                int h = i >> 6, w = i & 63;
                float acc = 0.f;
#pragma unroll
                for (int kw = 0; kw < 16; kw++) {
                    int j = (kw * w) & 63;
                    float2 yv = Yl[h * 17 + kw];
                    float term = yv.x * ct[j] - yv.y * st[j];
                    acc += (kw == 0) ? term : 2.0f * term;
                }
                s_tl[h * 65 + w] = acc;
            }
            __syncthreads();
            if (l < 3) {
                for (int i = tid; i < PIX; i += 256) {
                    int h = i >> 6, w = i & 63;
                    float v = s_tl[h * 65 + w] + a.skb[l * 12 + oc];
                    for (int c = 0; c < 12; c++)
                        v += tin[(b * 12 + c) * PIX + i] * a.skw[l * 144 + c * 12 + oc];
                    v = gelu_f(v);
                    s_tl[h * 65 + w] = v;
                    tout[(b * 12 + oc) * PIX + i] = v;
                }
                __syncthreads();
                fwd_w_tile(s_tl, ct, st, blk, a.A, tid);
            } else {
                for (int i = tid; i < PIX; i += 256)
                    a.spec[blk * PIX + i] = s_tl[(i >> 6) * 65 + (i & 63)];
            }
        }
        gbar(&a.bar[bi++]);

        if (l < 3) { const float* tmp = tin; tin = tout; tout = (float*)tmp; }
    }

    // ---- P5: final skip (no gelu), px-partitioned -> t_final in tout (= t0) ----
    {
        int p = blk * 256 + tid;
        int b = p >> 12, px = p & 4095;
        float tr[12];
#pragma unroll
        for (int c = 0; c < 12; c++) tr[c] = tin[(b * 12 + c) * PIX + px];
#pragma unroll
        for (int o = 0; o < 12; o++) {
            float v = a.spec[(b * 12 + o) * PIX + px] + a.skb[36 + o];
#pragma unroll
            for (int c = 0; c < 12; c++) v += tr[c] * a.skw[432 + c * 12 + o];
            tout[(b * 12 + o) * PIX + px] = v;
        }
    }
}

// ---------------- projection: q once per px-tile, loop over all 5 e-blocks ----------------
__global__ __launch_bounds__(256, 2) void k_proj2(const float* __restrict__ t,
                                                  const float* __restrict__ p1w,
                                                  const float* __restrict__ p1b,
                                                  const _Float16* __restrict__ wt,
                                                  const float* __restrict__ p2b,
                                                  const float* __restrict__ brn,
                                                  float* __restrict__ out) {
    __shared__ __align__(16) _Float16 ql[128 * 256];  // 64 KB, fragment order
    int pxb = blockIdx.x * 128;
    int tid = threadIdx.x;

    // phase A: q = gelu(t . p1w + p1b) -> fp16 LDS fragment layout (once)
    {
        int pxl = tid & 127;
        int dg  = tid >> 7;
        int px  = pxb + pxl;
        int b = px >> 12, pimg = px & 4095;
        float tv[12];
#pragma unroll
        for (int c = 0; c < 12; c++) tv[c] = t[(b * 12 + c) * PIX + pimg];
        int pg = pxl >> 5, pm = pxl & 31;
        for (int dd = 0; dd < 128; dd += 8) {
            half8 hv;
#pragma unroll
            for (int i = 0; i < 8; i++) {
                int d = dg * 128 + dd + i;
                float aa = p1b[d];
#pragma unroll
                for (int c = 0; c < 12; c++) aa += tv[c] * p1w[c * 256 + d];
                hv[i] = (_Float16)gelu_f(aa);
            }
            int d0 = dg * 128 + dd;
            int ks = d0 >> 4, kh = (d0 >> 3) & 1;
            *(half8*)&ql[pg * 8192 + ks * 512 + kh * 256 + pm * 8] = hv;
        }
    }
    __syncthreads();

    int wave = tid >> 6, lane = tid & 63;
    int we = wave >> 1, wp = wave & 1;
    int lo = (lane >> 5) * 256 + (lane & 31) * 8;
    int pg0 = wp * 2;
    float brv = brn[pxb >> 12];

    for (int ebi = 0; ebi < 5; ebi++) {
        int eb = ebi * 128;
        int eg0 = (eb + we * 64) >> 5;

        floatx16 acc[2][2];
#pragma unroll
        for (int aa = 0; aa < 2; aa++)
#pragma unroll
            for (int b2 = 0; b2 < 2; b2++)
#pragma unroll
                for (int i = 0; i < 16; i++) acc[aa][b2][i] = 0.f;

#pragma unroll
        for (int ks = 0; ks < 16; ks++) {
            half8 a0 = *(const half8*)(wt + eg0 * 8192 + ks * 512 + lo);
            half8 a1 = *(const half8*)(wt + (eg0 + 1) * 8192 + ks * 512 + lo);
            half8 b0 = *(const half8*)&ql[pg0 * 8192 + ks * 512 + lo];
            half8 b1 = *(const half8*)&ql[(pg0 + 1) * 8192 + ks * 512 + lo];
            acc[0][0] = __builtin_amdgcn_mfma_f32_32x32x16_f16(a0, b0, acc[0][0], 0, 0, 0);
            acc[0][1] = __builtin_amdgcn_mfma_f32_32x32x16_f16(a0, b1, acc[0][1], 0, 0, 0);
            acc[1][0] = __builtin_amdgcn_mfma_f32_32x32x16_f16(a1, b0, acc[1][0], 0, 0, 0);
            acc[1][1] = __builtin_amdgcn_mfma_f32_32x32x16_f16(a1, b1, acc[1][1], 0, 0, 0);
        }

#pragma unroll
        for (int ta = 0; ta < 2; ta++) {
#pragma unroll
            for (int tb = 0; tb < 2; tb++) {
                int e_base = eb + we * 64 + ta * 32;
                int px = pxb + wp * 64 + tb * 32 + (lane & 31);
                int bh = px >> 6, w = px & 63;
                float* op = out + bh * 640 * 64 + w;
#pragma unroll
                for (int r = 0; r < 16; r++) {
                    int row = (r & 3) + 8 * (r >> 2) + 4 * (lane >> 5);
                    int e = e_base + row;
                    op[e * 64] = (acc[ta][tb][r] + p2b[e]) * brv;
                }
            }
        }
    }
}

extern "C" void kernel_launch(void* const* d_in, const int* in_sizes, int n_in,
                              void* d_out, int out_size, void* d_ws, size_t ws_size,
                              hipStream_t stream) {
    float* ws = (float*)d_ws;
    unsigned* bar = (unsigned*)ws;          // 16 slots (64 B)
    float* brn  = ws + 16;                  // 16
    float* t0   = ws + 32;                  // 786432
    float* t1   = t0 + 786432;              // 786432
    float2* A   = (float2*)(t1 + 786432);   // 196608 float2
    float2* O   = A + 196608;               // 98304 float2
    float* spec = (float*)(O + 98304);      // 786432
    _Float16* wt = (_Float16*)(spec + 786432);  // 163840 halfs

    hipMemsetAsync(bar, 0, 64, stream);     // zero the barrier slots (ws is poisoned each call)

    FusedArgs fa;
    fa.x = (const float*)d_in[0];   fa.cond = (const float*)d_in[1];
    fa.bn2_g = (const float*)d_in[2]; fa.bn2_b = (const float*)d_in[3];
    fa.bn1_g = (const float*)d_in[4]; fa.bn1_b = (const float*)d_in[5];
    fa.b_w1 = (const float*)d_in[6];  fa.b_b1 = (const float*)d_in[7];
    fa.b_w2 = (const float*)d_in[8];  fa.b_b2 = (const float*)d_in[9];
    fa.b_w3 = (const float*)d_in[10]; fa.b_b3 = (const float*)d_in[11];
    fa.l1w = (const float*)d_in[12];  fa.l1b = (const float*)d_in[13];
    fa.l2w = (const float*)d_in[14];  fa.l2b = (const float*)d_in[15];
    fa.sw1r = (const float*)d_in[16]; fa.sw1i = (const float*)d_in[17];
    fa.sw2r = (const float*)d_in[18]; fa.sw2i = (const float*)d_in[19];
    fa.skw = (const float*)d_in[20];  fa.skb = (const float*)d_in[21];
    fa.p2w = (const float*)d_in[24];
    fa.bar = bar;
    fa.brn = brn; fa.t0 = t0; fa.t1 = t1; fa.A = A; fa.O = O; fa.spec = spec; fa.wt = wt;

    k_fused<<<256, 256, 0, stream>>>(fa);

    const float* p1w = (const float*)d_in[22];
    const float* p1b = (const float*)d_in[23];
    const float* p2b = (const float*)d_in[25];
    k_proj2<<<512, 256, 0, stream>>>(t0, p1w, p1b, wt, p2b, brn, (float*)d_out);
}